// Round 2
// baseline (2995.870 us; speedup 1.0000x reference)
//
#include <hip/hip_runtime.h>
#include <hip/hip_bf16.h>
#include <math.h>

#define K_OFF 27

// ---------------------------------------------------------------------------
// Build dense per-output neighbor table: table[out*27 + k] = in_row, or -1.
// Race-free: each (out, k) appears at most once in the kernel map.
// Padding entries have in == n_in (dummy row) -> skipped.
// ---------------------------------------------------------------------------
__global__ void build_table_kernel(const int* __restrict__ in_idx,
                                   const int* __restrict__ out_idx,
                                   int* __restrict__ table,
                                   int M, int n_in, int n_out) {
  int j = blockIdx.x * blockDim.x + threadIdx.x;
  if (j >= K_OFF * M) return;
  int k = j / M;
  int in = in_idx[j];
  int out = out_idx[j];
  if (in < n_in && out < n_out)
    table[out * K_OFF + k] = in;
}

// ---------------------------------------------------------------------------
// Implicit-GEMM sparse conv: y[o, :] = sum_k  x[table[o,k], :] @ W[k]
// Block tile: BM=64 rows x BN=128 cols, BK=32, 256 threads, fp32 VALU.
// No atomics: each block owns its output tile exclusively.
// ---------------------------------------------------------------------------
template <int CIN>
__global__ __launch_bounds__(256, 2) void spconv_kernel(
    const float* __restrict__ x, const float* __restrict__ W,
    const int* __restrict__ table, float* __restrict__ y,
    int n_out, int Cout) {
  constexpr int BM = 64, BN = 128, BK = 32;
  __shared__ float A_s[BK][BM + 4];   // transposed: A_s[kk][row]
  __shared__ float W_s[BK][BN + 4];
  __shared__ int idx_s[BM];

  const int tid = threadIdx.x;
  const int row0 = blockIdx.x * BM;
  const int col0 = blockIdx.y * BN;
  const int ty = tid >> 4;        // 0..15 -> rows ty*4 .. ty*4+3
  const int tx = tid & 15;        // 0..15 -> cols tx*8 .. tx*8+7

  float acc[4][8];
#pragma unroll
  for (int i = 0; i < 4; ++i)
#pragma unroll
    for (int j = 0; j < 8; ++j) acc[i][j] = 0.f;

  const int ar = tid >> 2;          // 0..63   gather row
  const int ac = (tid & 3) * 8;     // 0,8,16,24
  const int wr = tid >> 3;          // 0..31   W tile row
  const int wc = (tid & 7) * 16;    // col base, 16 floats per thread

  for (int k = 0; k < K_OFF; ++k) {
    if (tid < BM) {
      int o = row0 + tid;
      idx_s[tid] = (o < n_out) ? table[o * K_OFF + k] : -1;
    }
    __syncthreads();
    for (int kk0 = 0; kk0 < CIN; kk0 += BK) {
      // ---- gather A tile (64 rows x 32 cols), zeros for missing neighbors
      float4 a0 = make_float4(0.f, 0.f, 0.f, 0.f), a1 = a0;
      int irow = idx_s[ar];
      if (irow >= 0) {
        const float4* src =
            reinterpret_cast<const float4*>(x + (size_t)irow * CIN + kk0 + ac);
        a0 = src[0];
        a1 = src[1];
      }
      A_s[ac + 0][ar] = a0.x; A_s[ac + 1][ar] = a0.y;
      A_s[ac + 2][ar] = a0.z; A_s[ac + 3][ar] = a0.w;
      A_s[ac + 4][ar] = a1.x; A_s[ac + 5][ar] = a1.y;
      A_s[ac + 6][ar] = a1.z; A_s[ac + 7][ar] = a1.w;
      // ---- load W tile (32 x 128)
      const float4* wsrc = reinterpret_cast<const float4*>(
          W + ((size_t)k * CIN + kk0 + wr) * Cout + col0 + wc);
      float4 w0 = wsrc[0], w1 = wsrc[1], w2 = wsrc[2], w3 = wsrc[3];
      float4* wdst = reinterpret_cast<float4*>(&W_s[wr][wc]);
      wdst[0] = w0; wdst[1] = w1; wdst[2] = w2; wdst[3] = w3;
      __syncthreads();
      // ---- FMA accumulate
#pragma unroll
      for (int kk = 0; kk < BK; ++kk) {
        const float4 av = *reinterpret_cast<const float4*>(&A_s[kk][ty * 4]);
        const float4 wv0 = *reinterpret_cast<const float4*>(&W_s[kk][tx * 8]);
        const float4 wv1 = *reinterpret_cast<const float4*>(&W_s[kk][tx * 8 + 4]);
        const float aa[4] = {av.x, av.y, av.z, av.w};
        const float ww[8] = {wv0.x, wv0.y, wv0.z, wv0.w,
                             wv1.x, wv1.y, wv1.z, wv1.w};
#pragma unroll
        for (int i = 0; i < 4; ++i)
#pragma unroll
          for (int j = 0; j < 8; ++j)
            acc[i][j] = fmaf(aa[i], ww[j], acc[i][j]);
      }
      __syncthreads();
    }
  }
#pragma unroll
  for (int i = 0; i < 4; ++i) {
    int r = row0 + ty * 4 + i;
    if (r < n_out) {
      float4* dst =
          reinterpret_cast<float4*>(y + (size_t)r * Cout + col0 + tx * 8);
      dst[0] = make_float4(acc[i][0], acc[i][1], acc[i][2], acc[i][3]);
      dst[1] = make_float4(acc[i][4], acc[i][5], acc[i][6], acc[i][7]);
    }
  }
}

// ---------------------------------------------------------------------------
// Column sums / sum-of-squares in double (64 rows per block, C threads).
// ---------------------------------------------------------------------------
__global__ void colstats_kernel(const float* __restrict__ y, int n, int C,
                                double* __restrict__ sums) {
  const int c = threadIdx.x;  // blockDim.x == C
  const int r0 = blockIdx.x * 64;
  const int r1 = min(r0 + 64, n);
  double s = 0.0, s2 = 0.0;
  for (int r = r0; r < r1; ++r) {
    float v = y[(size_t)r * C + c];
    s += v;
    s2 += (double)v * (double)v;
  }
  atomicAdd(&sums[c], s);
  atomicAdd(&sums[C + c], s2);
}

__global__ void finalize_kernel(const double* __restrict__ sums,
                                const float* __restrict__ g,
                                const float* __restrict__ b,
                                float* __restrict__ scale,
                                float* __restrict__ shift, int n, int C) {
  int c = blockIdx.x * blockDim.x + threadIdx.x;
  if (c >= C) return;
  double m = sums[c] / n;
  double v = sums[C + c] / n - m * m;
  float sc = (float)((double)g[c] / sqrt(v + 1e-5));
  scale[c] = sc;
  shift[c] = b[c] - (float)m * sc;
}

// BN + ReLU + segment-max pool (atomicMax on uint bits; values >= 0).
__global__ void bn_relu_pool_kernel(const float* __restrict__ y,
                                    const float* __restrict__ scale,
                                    const float* __restrict__ shift,
                                    const int* __restrict__ parent,
                                    unsigned int* __restrict__ pooled, int n,
                                    int C) {
  int i4 = (blockIdx.x * blockDim.x + threadIdx.x) * 4;
  if (i4 >= n * C) return;
  int r = i4 / C, c = i4 % C;
  float4 v = *reinterpret_cast<const float4*>(y + i4);
  float4 sc = *reinterpret_cast<const float4*>(scale + c);
  float4 sh = *reinterpret_cast<const float4*>(shift + c);
  unsigned int* dst = pooled + (size_t)parent[r] * C + c;
  atomicMax(dst + 0, __float_as_uint(fmaxf(fmaf(v.x, sc.x, sh.x), 0.f)));
  atomicMax(dst + 1, __float_as_uint(fmaxf(fmaf(v.y, sc.y, sh.y), 0.f)));
  atomicMax(dst + 2, __float_as_uint(fmaxf(fmaf(v.z, sc.z, sh.z), 0.f)));
  atomicMax(dst + 3, __float_as_uint(fmaxf(fmaf(v.w, sc.w, sh.w), 0.f)));
}

// BN + ReLU in place.
__global__ void bn_relu_kernel(float* __restrict__ y,
                               const float* __restrict__ scale,
                               const float* __restrict__ shift, int total,
                               int C) {
  int i4 = (blockIdx.x * blockDim.x + threadIdx.x) * 4;
  if (i4 >= total) return;
  int c = i4 % C;
  float4 v = *reinterpret_cast<float4*>(y + i4);
  float4 sc = *reinterpret_cast<const float4*>(scale + c);
  float4 sh = *reinterpret_cast<const float4*>(shift + c);
  v.x = fmaxf(fmaf(v.x, sc.x, sh.x), 0.f);
  v.y = fmaxf(fmaf(v.y, sc.y, sh.y), 0.f);
  v.z = fmaxf(fmaf(v.z, sc.z, sh.z), 0.f);
  v.w = fmaxf(fmaf(v.w, sc.w, sh.w), 0.f);
  *reinterpret_cast<float4*>(y + i4) = v;
}

// ---------------------------------------------------------------------------
extern "C" void kernel_launch(void* const* d_in, const int* in_sizes, int n_in,
                              void* d_out, int out_size, void* d_ws,
                              size_t ws_size, hipStream_t stream) {
  const float* feats = (const float*)d_in[0];
  const float* W1 = (const float*)d_in[1];
  const float* g1 = (const float*)d_in[2];
  const float* b1 = (const float*)d_in[3];
  const float* W2 = (const float*)d_in[4];
  const float* g2 = (const float*)d_in[5];
  const float* b2 = (const float*)d_in[6];
  const float* W3 = (const float*)d_in[7];
  const float* g3 = (const float*)d_in[8];
  const float* b3 = (const float*)d_in[9];
  const float* W4 = (const float*)d_in[10];
  const int* in1 = (const int*)d_in[11];
  const int* out1 = (const int*)d_in[12];
  const int* in2 = (const int*)d_in[13];
  const int* out2 = (const int*)d_in[14];
  const int* parent = (const int*)d_in[15];

  const int N1 = in_sizes[0] / 128;   // 60000
  const int M1 = in_sizes[11] / K_OFF;
  const int M2 = in_sizes[13] / K_OFF;
  const int NP = out_size / 256;      // n_pool

  // ---- workspace layout (256B-aligned chunks) ----
  const size_t sz_t1 = (size_t)N1 * K_OFF * 4;
  const size_t sz_t2 = (size_t)NP * K_OFF * 4;
  const size_t sz_y1 = (size_t)N1 * 128 * 4;
  const size_t sz_pool = (size_t)NP * 128 * 4;
  const size_t sz_y23 = (size_t)NP * 256 * 4;
  auto rnd = [](size_t v) { return (v + 255) & ~size_t(255); };

  char* ws = (char*)d_ws;
  size_t off = 0;
  auto take = [&](size_t bytes) {
    void* p = ws + off;
    off += rnd(bytes);
    return p;
  };

  // Plain layout size check; overlapped fallback if workspace is tight.
  size_t plain = rnd(sz_t1) + rnd(sz_t2) + rnd(sz_y1) + rnd(sz_pool) +
                 2 * rnd(sz_y23) + 3 * rnd(2 * 256 * 8) + 3 * rnd(2 * 256 * 4);
  bool overlap = (plain > ws_size) && ((size_t)2 * rnd(sz_y23) <= sz_y1) &&
                 (sz_pool <= sz_t1);

  float* y1 = (float*)take(sz_y1);
  int* table1 = (int*)take(sz_t1);
  int* table2 = (int*)take(sz_t2);
  float* pooled;
  float* y2;
  float* y3;
  if (overlap) {
    pooled = (float*)table1;                 // table1 dead after conv1
    y2 = y1;                                 // y1 dead after pooling
    y3 = (float*)((char*)y1 + rnd(sz_y23));
  } else {
    pooled = (float*)take(sz_pool);
    y2 = (float*)take(sz_y23);
    y3 = (float*)take(sz_y23);
  }
  double* sums1 = (double*)take(2 * 256 * 8);
  double* sums2 = (double*)take(2 * 256 * 8);
  double* sums3 = (double*)take(2 * 256 * 8);
  float* sc1 = (float*)take(2 * 128 * 4); float* sh1 = sc1 + 128;
  float* sc2 = (float*)take(2 * 256 * 4); float* sh2 = sc2 + 256;
  float* sc3 = (float*)take(2 * 256 * 4); float* sh3 = sc3 + 256;

  hipMemsetAsync(table1, 0xFF, sz_t1, stream);
  hipMemsetAsync(table2, 0xFF, sz_t2, stream);
  hipMemsetAsync(sums1, 0, 2 * 256 * 8, stream);
  hipMemsetAsync(sums2, 0, 2 * 256 * 8, stream);
  hipMemsetAsync(sums3, 0, 2 * 256 * 8, stream);

  build_table_kernel<<<(K_OFF * M1 + 255) / 256, 256, 0, stream>>>(
      in1, out1, table1, M1, N1, N1);
  build_table_kernel<<<(K_OFF * M2 + 255) / 256, 256, 0, stream>>>(
      in2, out2, table2, M2, NP, NP);

  // conv1: 128 -> 128
  dim3 gc1((N1 + 63) / 64, 1);
  spconv_kernel<128><<<gc1, 256, 0, stream>>>(feats, W1, table1, y1, N1, 128);
  colstats_kernel<<<(N1 + 63) / 64, 128, 0, stream>>>(y1, N1, 128, sums1);
  finalize_kernel<<<1, 128, 0, stream>>>(sums1, g1, b1, sc1, sh1, N1, 128);
  // pooled init AFTER conv1 (may alias table1)
  hipMemsetAsync(pooled, 0, sz_pool, stream);
  bn_relu_pool_kernel<<<((N1 * 128 / 4) + 255) / 256, 256, 0, stream>>>(
      y1, sc1, sh1, parent, (unsigned int*)pooled, N1, 128);

  // conv2: 128 -> 256
  dim3 gc2((NP + 63) / 64, 2);
  spconv_kernel<128><<<gc2, 256, 0, stream>>>(pooled, W2, table2, y2, NP, 256);
  colstats_kernel<<<(NP + 63) / 64, 256, 0, stream>>>(y2, NP, 256, sums2);
  finalize_kernel<<<1, 256, 0, stream>>>(sums2, g2, b2, sc2, sh2, NP, 256);
  bn_relu_kernel<<<((NP * 256 / 4) + 255) / 256, 256, 0, stream>>>(
      y2, sc2, sh2, NP * 256, 256);

  // conv3: 256 -> 256
  spconv_kernel<256><<<gc2, 256, 0, stream>>>(y2, W3, table2, y3, NP, 256);
  colstats_kernel<<<(NP + 63) / 64, 256, 0, stream>>>(y3, NP, 256, sums3);
  finalize_kernel<<<1, 256, 0, stream>>>(sums3, g3, b3, sc3, sh3, NP, 256);
  bn_relu_kernel<<<((NP * 256 / 4) + 255) / 256, 256, 0, stream>>>(
      y3, sc3, sh3, NP * 256, 256);

  // conv4: 256 -> 256, straight to output
  spconv_kernel<256><<<gc2, 256, 0, stream>>>(y3, W4, table2, (float*)d_out,
                                              NP, 256);
}

// Round 8
// 827.798 us; speedup vs baseline: 3.6191x; 3.6191x over previous
//
#include <hip/hip_runtime.h>
#include <hip/hip_bf16.h>
#include <math.h>

#define K_OFF 27

typedef __attribute__((ext_vector_type(8))) short short8v;   // 8 x bf16 (4 VGPR)
typedef __attribute__((ext_vector_type(4))) float float4v;   // MFMA C/D

static __device__ __forceinline__ unsigned short f2bf(float f) {
  __hip_bfloat16 h = __float2bfloat16(f);
  return *reinterpret_cast<unsigned short*>(&h);
}

static __device__ __forceinline__ void gload_lds16(const void* g, void* l) {
  __builtin_amdgcn_global_load_lds(
      (const __attribute__((address_space(1))) void*)g,
      (__attribute__((address_space(3))) void*)l, 16, 0, 0);
}

// ---------------------------------------------------------------------------
__global__ void fill_i32_kernel(int* __restrict__ p, int total, int val) {
  int i = blockIdx.x * blockDim.x + threadIdx.x;
  if (i < total) p[i] = val;
}

// k-major table: table[k*n_out_pad + out] = in  (default: n_valid = zero row)
__global__ void build_table_kernel(const int* __restrict__ in_idx,
                                   const int* __restrict__ out_idx,
                                   int* __restrict__ table, int M, int n_valid,
                                   int n_out_pad) {
  int j = blockIdx.x * blockDim.x + threadIdx.x;
  if (j >= K_OFF * M) return;
  int k = j / M;
  int in = in_idx[j], out = out_idx[j];
  if (in < n_valid && out < n_valid) table[k * n_out_pad + out] = in;
}

// W[k][ci][co] f32 -> Wt[k][co][ci] bf16 (tiled 32x32 transpose)
__global__ void wtrans_kernel(const float* __restrict__ W,
                              unsigned short* __restrict__ Wt, int Cin,
                              int Cout) {
  __shared__ float t[32][33];
  const int k = blockIdx.z, ci0 = blockIdx.x * 32, co0 = blockIdx.y * 32;
  const float* Wk = W + (size_t)k * Cin * Cout;
  unsigned short* Wtk = Wt + (size_t)k * Cout * Cin;
#pragma unroll
  for (int i = 0; i < 4; ++i)
    t[threadIdx.y + i * 8][threadIdx.x] =
        Wk[(size_t)(ci0 + threadIdx.y + i * 8) * Cout + co0 + threadIdx.x];
  __syncthreads();
#pragma unroll
  for (int i = 0; i < 4; ++i)
    Wtk[(size_t)(co0 + threadIdx.y + i * 8) * Cin + ci0 + threadIdx.x] =
        f2bf(t[threadIdx.x][threadIdx.y + i * 8]);
}

__global__ void f32_to_bf16_kernel(const float* __restrict__ s,
                                   unsigned short* __restrict__ d, int total) {
  int i = (blockIdx.x * blockDim.x + threadIdx.x) * 4;
  if (i >= total) return;
  float4 v = *reinterpret_cast<const float4*>(s + i);
  ushort4 o = {f2bf(v.x), f2bf(v.y), f2bf(v.z), f2bf(v.w)};
  *reinterpret_cast<ushort4*>(d + i) = o;
}

// ---------------------------------------------------------------------------
// bf16-MFMA implicit-GEMM sparse conv.
// y[o, col] = sum_k sum_ci xb[table[k][o]][ci] * Wt[k][col][ci]
// 128x128 tile, 4 waves (2x2 of 64x64), BK=32, double-buffered LDS,
// global_load_lds(16B) staging (A gathered per-lane), chunk-XOR bank swizzle.
// ---------------------------------------------------------------------------
template <int CIN>
__global__ __launch_bounds__(256) void spconv_mfma(
    const unsigned short* __restrict__ xb,   // [(n_in+1) x CIN] bf16 (last row 0)
    const unsigned short* __restrict__ Wt,   // [K_OFF x Cout x CIN] bf16
    const int* __restrict__ table,           // [K_OFF x n_out_pad]
    float* __restrict__ y, int n_out, int n_out_pad, int Cout) {
  constexpr int BK = 32;
  constexpr int SPK = CIN / BK;
  const int S = K_OFF * SPK;

  __shared__ unsigned short As[2][128 * BK];
  __shared__ unsigned short Bs[2][128 * BK];
  __shared__ int idx_s[K_OFF * 128];

  const int tid = threadIdx.x;
  const int lane = tid & 63;
  const int wid = tid >> 6;
  const int row0 = blockIdx.x * 128;
  const int col0 = blockIdx.y * 128;
  const int wr = wid >> 1, wc = wid & 1;

  for (int j = tid; j < K_OFF * 128; j += 256)
    idx_s[j] = table[(j >> 7) * n_out_pad + row0 + (j & 127)];
  __syncthreads();

  const int srow = tid >> 2;   // 0..63
  const int sc4 = tid & 3;     // 16B chunk within 64B row-slice

  auto stage = [&](int buf, int s) {
    const int k = s / SPK;
    const int kk0 = (s % SPK) * BK;
    const int* idk = &idx_s[k << 7];
#pragma unroll
    for (int r = 0; r < 2; ++r) {
      const int row = r * 64 + srow;
      const int cg = sc4 ^ ((row >> 1) & 3);   // pre-swizzled global chunk
      const int irow = idk[row];
      const unsigned short* srcA = xb + (size_t)irow * CIN + kk0 + cg * 8;
      gload_lds16(srcA, (void*)&As[buf][(r * 64 + wid * 16) * BK]);
      const unsigned short* srcB =
          Wt + ((size_t)k * Cout + col0 + row) * CIN + kk0 + cg * 8;
      gload_lds16(srcB, (void*)&Bs[buf][(r * 64 + wid * 16) * BK]);
    }
  };

  // Fragment LDS element offsets (buf-invariant). Read applies same swizzle.
  int a_off[4], b_off[4];
#pragma unroll
  for (int mi = 0; mi < 4; ++mi) {
    const int row = wr * 64 + mi * 16 + (lane & 15);
    const int ca = (lane >> 4) ^ ((row >> 1) & 3);
    a_off[mi] = row * BK + ca * 8;
    const int rowb = wc * 64 + mi * 16 + (lane & 15);
    const int cb = (lane >> 4) ^ ((rowb >> 1) & 3);
    b_off[mi] = rowb * BK + cb * 8;
  }

  float4v acc[4][4];
#pragma unroll
  for (int i = 0; i < 4; ++i)
#pragma unroll
    for (int j = 0; j < 4; ++j) acc[i][j] = (float4v)(0.f);

  stage(0, 0);
  for (int s = 0; s < S; ++s) {
    const int buf = s & 1;
    __syncthreads();               // drains stage(s): vmcnt(0) before barrier
    if (s + 1 < S) stage(buf ^ 1, s + 1);
    short8v a[4], b[4];
#pragma unroll
    for (int i = 0; i < 4; ++i) {
      a[i] = *reinterpret_cast<const short8v*>(&As[buf][a_off[i]]);
      b[i] = *reinterpret_cast<const short8v*>(&Bs[buf][b_off[i]]);
    }
#pragma unroll
    for (int mi = 0; mi < 4; ++mi)
#pragma unroll
      for (int ni = 0; ni < 4; ++ni)
        acc[mi][ni] = __builtin_amdgcn_mfma_f32_16x16x32_bf16(
            a[mi], b[ni], acc[mi][ni], 0, 0, 0);
  }

  // Epilogue: C/D layout col=lane&15, row=(lane>>4)*4+j  [m89]
#pragma unroll
  for (int mi = 0; mi < 4; ++mi) {
    const int rbase = row0 + wr * 64 + mi * 16 + ((lane >> 4) << 2);
#pragma unroll
    for (int ni = 0; ni < 4; ++ni) {
      const int col = col0 + wc * 64 + ni * 16 + (lane & 15);
#pragma unroll
      for (int j = 0; j < 4; ++j) {
        const int r = rbase + j;
        if (r < n_out) y[(size_t)r * Cout + col] = acc[mi][ni][j];
      }
    }
  }
}

// ---------------------------------------------------------------------------
__global__ void colstats_kernel(const float* __restrict__ y, int n, int C,
                                double* __restrict__ sums) {
  const int c = threadIdx.x;  // blockDim.x == C
  const int r0 = blockIdx.x * 64;
  const int r1 = min(r0 + 64, n);
  double s = 0.0, s2 = 0.0;
  for (int r = r0; r < r1; ++r) {
    float v = y[(size_t)r * C + c];
    s += v;
    s2 += (double)v * (double)v;
  }
  atomicAdd(&sums[c], s);
  atomicAdd(&sums[C + c], s2);
}

__global__ void finalize_kernel(const double* __restrict__ sums,
                                const float* __restrict__ g,
                                const float* __restrict__ b,
                                float* __restrict__ scale,
                                float* __restrict__ shift, int n, int C) {
  int c = blockIdx.x * blockDim.x + threadIdx.x;
  if (c >= C) return;
  double m = sums[c] / n;
  double v = sums[C + c] / n - m * m;
  float sc = (float)((double)g[c] / sqrt(v + 1e-5));
  scale[c] = sc;
  shift[c] = b[c] - (float)m * sc;
}

__global__ void bn_relu_pool_kernel(const float* __restrict__ y,
                                    const float* __restrict__ scale,
                                    const float* __restrict__ shift,
                                    const int* __restrict__ parent,
                                    unsigned int* __restrict__ pooled, int n,
                                    int C) {
  int i4 = (blockIdx.x * blockDim.x + threadIdx.x) * 4;
  if (i4 >= n * C) return;
  int r = i4 / C, c = i4 % C;
  float4 v = *reinterpret_cast<const float4*>(y + i4);
  float4 sc = *reinterpret_cast<const float4*>(scale + c);
  float4 sh = *reinterpret_cast<const float4*>(shift + c);
  unsigned int* dst = pooled + (size_t)parent[r] * C + c;
  atomicMax(dst + 0, __float_as_uint(fmaxf(fmaf(v.x, sc.x, sh.x), 0.f)));
  atomicMax(dst + 1, __float_as_uint(fmaxf(fmaf(v.y, sc.y, sh.y), 0.f)));
  atomicMax(dst + 2, __float_as_uint(fmaxf(fmaf(v.z, sc.z, sh.z), 0.f)));
  atomicMax(dst + 3, __float_as_uint(fmaxf(fmaf(v.w, sc.w, sh.w), 0.f)));
}

__global__ void bn_relu_bf16_kernel(const float* __restrict__ y,
                                    const float* __restrict__ scale,
                                    const float* __restrict__ shift,
                                    unsigned short* __restrict__ xb, int total,
                                    int C) {
  int i4 = (blockIdx.x * blockDim.x + threadIdx.x) * 4;
  if (i4 >= total) return;
  int c = i4 % C;
  float4 v = *reinterpret_cast<const float4*>(y + i4);
  float4 sc = *reinterpret_cast<const float4*>(scale + c);
  float4 sh = *reinterpret_cast<const float4*>(shift + c);
  ushort4 o = {f2bf(fmaxf(fmaf(v.x, sc.x, sh.x), 0.f)),
               f2bf(fmaxf(fmaf(v.y, sc.y, sh.y), 0.f)),
               f2bf(fmaxf(fmaf(v.z, sc.z, sh.z), 0.f)),
               f2bf(fmaxf(fmaf(v.w, sc.w, sh.w), 0.f))};
  *reinterpret_cast<ushort4*>(xb + i4) = o;
}

// ---------------------------------------------------------------------------
extern "C" void kernel_launch(void* const* d_in, const int* in_sizes, int n_in_,
                              void* d_out, int out_size, void* d_ws,
                              size_t ws_size, hipStream_t stream) {
  const float* feats = (const float*)d_in[0];
  const float* W1 = (const float*)d_in[1];
  const float* g1 = (const float*)d_in[2];
  const float* b1 = (const float*)d_in[3];
  const float* W2 = (const float*)d_in[4];
  const float* g2 = (const float*)d_in[5];
  const float* b2 = (const float*)d_in[6];
  const float* W3 = (const float*)d_in[7];
  const float* g3 = (const float*)d_in[8];
  const float* b3 = (const float*)d_in[9];
  const float* W4 = (const float*)d_in[10];
  const int* in1 = (const int*)d_in[11];
  const int* out1 = (const int*)d_in[12];
  const int* in2 = (const int*)d_in[13];
  const int* out2 = (const int*)d_in[14];
  const int* parent = (const int*)d_in[15];

  const int N1 = in_sizes[0] / 128;        // 60000
  const int M1 = in_sizes[11] / K_OFF;
  const int M2 = in_sizes[13] / K_OFF;
  const int NP = out_size / 256;           // n_pool

  const int n1_blocks = (N1 + 127) / 128, n1_pad = n1_blocks * 128;
  const int np_blocks = (NP + 127) / 128, np_pad = np_blocks * 128;

  auto rnd = [](size_t v) { return (v + 255) & ~size_t(255); };
  auto mx = [](size_t a, size_t b) { return a > b ? a : b; };
  char* ws = (char*)d_ws;
  size_t off = 0;
  auto take = [&](size_t b) { void* p = ws + off; off += rnd(b); return p; };

  const size_t sz_y1 = (size_t)N1 * 128 * 4;
  const size_t sz_y23 = (size_t)NP * 256 * 4;
  const size_t sz_x1 = ((size_t)N1 + 1) * 128 * 2;
  const size_t sz_x23 = ((size_t)NP + 1) * 256 * 2;
  const size_t sz_t1 = (size_t)K_OFF * n1_pad * 4;
  const size_t sz_t2 = (size_t)K_OFF * np_pad * 4;
  const size_t sz_pool = (size_t)NP * 128 * 4;
  const size_t sz_poolbf = ((size_t)NP + 1) * 128 * 2;
  const size_t sz_wt2 = (size_t)K_OFF * 128 * 256 * 2;
  const size_t sz_wt34 = (size_t)K_OFF * 256 * 256 * 2;

  // Slab A: y1  ->  {y2, y3}
  char* A = (char*)take(mx(rnd(sz_y1), 2 * rnd(sz_y23)));
  float* y1 = (float*)A;
  float* y2 = (float*)A;
  float* y3 = (float*)(A + rnd(sz_y23));
  // Slab B: x1b  ->  {Wt2, Wt3, Wt4, poolbf}   (Wt2-4 transposed AFTER conv1)
  char* B = (char*)take(
      mx(rnd(sz_x1), rnd(sz_wt2) + 2 * rnd(sz_wt34) + rnd(sz_poolbf)));
  unsigned short* x1b = (unsigned short*)B;
  unsigned short* Wt2 = (unsigned short*)B;
  unsigned short* Wt3 = (unsigned short*)(B + rnd(sz_wt2));
  unsigned short* Wt4 = (unsigned short*)(B + rnd(sz_wt2) + rnd(sz_wt34));
  unsigned short* poolbf =
      (unsigned short*)(B + rnd(sz_wt2) + 2 * rnd(sz_wt34));
  // Slab C: table1 -> pooled -> x2b -> x3b
  char* C = (char*)take(mx(rnd(sz_t1), mx(rnd(sz_pool), rnd(sz_x23))));
  int* table1 = (int*)C;
  float* pooled = (float*)C;
  unsigned short* x2b = (unsigned short*)C;
  unsigned short* x3b = (unsigned short*)C;
  // Persistent
  int* table2 = (int*)take(sz_t2);
  unsigned short* Wt1 = (unsigned short*)take((size_t)K_OFF * 128 * 128 * 2);
  double* sums = (double*)take(3 * 512 * 8);
  double* sums1 = sums; double* sums2 = sums + 512; double* sums3 = sums + 1024;
  float* scsh = (float*)take(6 * 256 * 4);
  float* sc1 = scsh;        float* sh1 = scsh + 256;
  float* sc2 = scsh + 512;  float* sh2 = scsh + 768;
  float* sc3 = scsh + 1024; float* sh3 = scsh + 1280;

  dim3 wtb(32, 8);
  wtrans_kernel<<<dim3(4, 4, K_OFF), wtb, 0, stream>>>(W1, Wt1, 128, 128);

  f32_to_bf16_kernel<<<(N1 * 128 / 4 + 255) / 256, 256, 0, stream>>>(
      feats, x1b, N1 * 128);
  hipMemsetAsync(x1b + (size_t)N1 * 128, 0, 128 * 2, stream);

  fill_i32_kernel<<<(K_OFF * n1_pad + 255) / 256, 256, 0, stream>>>(
      table1, K_OFF * n1_pad, N1);
  fill_i32_kernel<<<(K_OFF * np_pad + 255) / 256, 256, 0, stream>>>(
      table2, K_OFF * np_pad, NP);
  build_table_kernel<<<(K_OFF * M1 + 255) / 256, 256, 0, stream>>>(
      in1, out1, table1, M1, N1, n1_pad);
  build_table_kernel<<<(K_OFF * M2 + 255) / 256, 256, 0, stream>>>(
      in2, out2, table2, M2, NP, np_pad);
  hipMemsetAsync(sums, 0, 3 * 512 * 8, stream);

  // conv1: 128 -> 128   (last use of x1b, table1, Wt1)
  spconv_mfma<128><<<dim3(n1_blocks, 1), 256, 0, stream>>>(
      x1b, Wt1, table1, y1, N1, n1_pad, 128);
  colstats_kernel<<<(N1 + 63) / 64, 128, 0, stream>>>(y1, N1, 128, sums1);
  finalize_kernel<<<1, 128, 0, stream>>>(sums1, g1, b1, sc1, sh1, N1, 128);
  // Wt2-4 into old x1b space (x1b dead after conv1; stream-ordered)
  wtrans_kernel<<<dim3(4, 8, K_OFF), wtb, 0, stream>>>(W2, Wt2, 128, 256);
  wtrans_kernel<<<dim3(8, 8, K_OFF), wtb, 0, stream>>>(W3, Wt3, 256, 256);
  wtrans_kernel<<<dim3(8, 8, K_OFF), wtb, 0, stream>>>(W4, Wt4, 256, 256);
  // pooled into old table1 space (table1 dead after conv1)
  hipMemsetAsync(pooled, 0, sz_pool, stream);
  bn_relu_pool_kernel<<<((N1 * 128 / 4) + 255) / 256, 256, 0, stream>>>(
      y1, sc1, sh1, parent, (unsigned int*)pooled, N1, 128);
  f32_to_bf16_kernel<<<((NP * 128 / 4) + 255) / 256, 256, 0, stream>>>(
      pooled, poolbf, NP * 128);
  hipMemsetAsync(poolbf + (size_t)NP * 128, 0, 128 * 2, stream);

  // conv2: 128 -> 256   (y2 overwrites y1 region; y1 dead after pool)
  spconv_mfma<128><<<dim3(np_blocks, 2), 256, 0, stream>>>(
      poolbf, Wt2, table2, y2, NP, np_pad, 256);
  colstats_kernel<<<(NP + 63) / 64, 256, 0, stream>>>(y2, NP, 256, sums2);
  finalize_kernel<<<1, 256, 0, stream>>>(sums2, g2, b2, sc2, sh2, NP, 256);
  bn_relu_bf16_kernel<<<((NP * 256 / 4) + 255) / 256, 256, 0, stream>>>(
      y2, sc2, sh2, x2b, NP * 256, 256);   // x2b overwrites pooled (dead)
  hipMemsetAsync(x2b + (size_t)NP * 256, 0, 256 * 2, stream);

  // conv3: 256 -> 256
  spconv_mfma<256><<<dim3(np_blocks, 2), 256, 0, stream>>>(
      x2b, Wt3, table2, y3, NP, np_pad, 256);
  colstats_kernel<<<(NP + 63) / 64, 256, 0, stream>>>(y3, NP, 256, sums3);
  finalize_kernel<<<1, 256, 0, stream>>>(sums3, g3, b3, sc3, sh3, NP, 256);
  bn_relu_bf16_kernel<<<((NP * 256 / 4) + 255) / 256, 256, 0, stream>>>(
      y3, sc3, sh3, x3b, NP * 256, 256);   // x3b overwrites x2b (dead)
  hipMemsetAsync(x3b + (size_t)NP * 256, 0, 256 * 2, stream);

  // conv4: 256 -> 256 -> d_out
  spconv_mfma<256><<<dim3(np_blocks, 2), 256, 0, stream>>>(
      x3b, Wt4, table2, (float*)d_out, NP, np_pad, 256);
}

// Round 10
// 769.722 us; speedup vs baseline: 3.8921x; 1.0755x over previous
//
#include <hip/hip_runtime.h>
#include <hip/hip_bf16.h>
#include <math.h>

#define K_OFF 27

typedef __attribute__((ext_vector_type(8))) short short8v;   // 8 x bf16 (4 VGPR)
typedef __attribute__((ext_vector_type(4))) float float4v;   // MFMA C/D

static __device__ __forceinline__ unsigned short f2bf(float f) {
  __hip_bfloat16 h = __float2bfloat16(f);
  return *reinterpret_cast<unsigned short*>(&h);
}

static __device__ __forceinline__ void gload_lds16(const void* g, void* l) {
  __builtin_amdgcn_global_load_lds(
      (const __attribute__((address_space(1))) void*)g,
      (__attribute__((address_space(3))) void*)l, 16, 0, 0);
}

// ---------------------------------------------------------------------------
__global__ void fill_i32_kernel(int* __restrict__ p, int total, int val) {
  int i = blockIdx.x * blockDim.x + threadIdx.x;
  if (i < total) p[i] = val;
}

// k-major table: table[k*n_out_pad + out] = in  (default: n_valid = zero row)
__global__ void build_table_kernel(const int* __restrict__ in_idx,
                                   const int* __restrict__ out_idx,
                                   int* __restrict__ table, int M, int n_valid,
                                   int n_out_pad) {
  int j = blockIdx.x * blockDim.x + threadIdx.x;
  if (j >= K_OFF * M) return;
  int k = j / M;
  int in = in_idx[j], out = out_idx[j];
  if (in < n_valid && out < n_valid) table[k * n_out_pad + out] = in;
}

// W[k][ci][co] f32 -> Wt[k][co][ci] bf16 (tiled 32x32 transpose)
__global__ void wtrans_kernel(const float* __restrict__ W,
                              unsigned short* __restrict__ Wt, int Cin,
                              int Cout) {
  __shared__ float t[32][33];
  const int k = blockIdx.z, ci0 = blockIdx.x * 32, co0 = blockIdx.y * 32;
  const float* Wk = W + (size_t)k * Cin * Cout;
  unsigned short* Wtk = Wt + (size_t)k * Cout * Cin;
#pragma unroll
  for (int i = 0; i < 4; ++i)
    t[threadIdx.y + i * 8][threadIdx.x] =
        Wk[(size_t)(ci0 + threadIdx.y + i * 8) * Cout + co0 + threadIdx.x];
  __syncthreads();
#pragma unroll
  for (int i = 0; i < 4; ++i)
    Wtk[(size_t)(co0 + threadIdx.y + i * 8) * Cin + ci0 + threadIdx.x] =
        f2bf(t[threadIdx.x][threadIdx.y + i * 8]);
}

__global__ void f32_to_bf16_kernel(const float* __restrict__ s,
                                   unsigned short* __restrict__ d, int total) {
  int i = (blockIdx.x * blockDim.x + threadIdx.x) * 4;
  if (i >= total) return;
  float4 v = *reinterpret_cast<const float4*>(s + i);
  ushort4 o = {f2bf(v.x), f2bf(v.y), f2bf(v.z), f2bf(v.w)};
  *reinterpret_cast<ushort4*>(d + i) = o;
}

// ---------------------------------------------------------------------------
// bf16-MFMA implicit-GEMM sparse conv, split-K over kernel offsets.
// Block (bx,by,g): output tile rows [bx*128,+128), cols [by*128,+128),
// offsets [g*KPG, (g+1)*KPG). Accumulates into y via f32 atomicAdd
// (y pre-zeroed). Grid.z = 27/KPG multiplies workgroups -> >=3 blocks/CU
// resident so per-step staging latency overlaps across blocks.
// ---------------------------------------------------------------------------
template <int CIN, int KPG>
__global__ __launch_bounds__(256) void spconv_mfma(
    const unsigned short* __restrict__ xb,   // [(n_in+1) x CIN] bf16 (last row 0)
    const unsigned short* __restrict__ Wt,   // [K_OFF x Cout x CIN] bf16
    const int* __restrict__ table,           // [K_OFF x n_out_pad]
    float* __restrict__ y, int n_out, int n_out_pad, int Cout) {
  constexpr int BK = 32;
  constexpr int SPK = CIN / BK;
  constexpr int S = KPG * SPK;

  __shared__ unsigned short As[2][128 * BK];
  __shared__ unsigned short Bs[2][128 * BK];
  __shared__ int idx_s[KPG * 128];

  const int tid = threadIdx.x;
  const int lane = tid & 63;
  const int wid = tid >> 6;
  const int row0 = blockIdx.x * 128;
  const int col0 = blockIdx.y * 128;
  const int kbase = blockIdx.z * KPG;
  const int wr = wid >> 1, wc = wid & 1;

  for (int j = tid; j < KPG * 128; j += 256)
    idx_s[j] = table[(kbase + (j >> 7)) * n_out_pad + row0 + (j & 127)];
  __syncthreads();

  const int srow = tid >> 2;   // 0..63
  const int sc4 = tid & 3;     // 16B chunk within 64B row-slice

  auto stage = [&](int buf, int s) {
    const int kl = s / SPK;                  // local offset index
    const int kk0 = (s % SPK) * BK;
    const int* idk = &idx_s[kl << 7];
#pragma unroll
    for (int r = 0; r < 2; ++r) {
      const int row = r * 64 + srow;
      const int cg = sc4 ^ ((row >> 1) & 3);   // pre-swizzled global chunk
      const int irow = idk[row];
      const unsigned short* srcA = xb + (size_t)irow * CIN + kk0 + cg * 8;
      gload_lds16(srcA, (void*)&As[buf][(r * 64 + wid * 16) * BK]);
      const unsigned short* srcB =
          Wt + ((size_t)(kbase + kl) * Cout + col0 + row) * CIN + kk0 + cg * 8;
      gload_lds16(srcB, (void*)&Bs[buf][(r * 64 + wid * 16) * BK]);
    }
  };

  // Fragment LDS element offsets (buf-invariant). Read applies same swizzle.
  int a_off[4], b_off[4];
#pragma unroll
  for (int mi = 0; mi < 4; ++mi) {
    const int row = wr * 64 + mi * 16 + (lane & 15);
    const int ca = (lane >> 4) ^ ((row >> 1) & 3);
    a_off[mi] = row * BK + ca * 8;
    const int rowb = wc * 64 + mi * 16 + (lane & 15);
    const int cb = (lane >> 4) ^ ((rowb >> 1) & 3);
    b_off[mi] = rowb * BK + cb * 8;
  }

  float4v acc[4][4];
#pragma unroll
  for (int i = 0; i < 4; ++i)
#pragma unroll
    for (int j = 0; j < 4; ++j) acc[i][j] = (float4v)(0.f);

  stage(0, 0);
  for (int s = 0; s < S; ++s) {
    const int buf = s & 1;
    __syncthreads();               // drains stage(s): vmcnt(0) before barrier
    if (s + 1 < S) stage(buf ^ 1, s + 1);
    short8v a[4], b[4];
#pragma unroll
    for (int i = 0; i < 4; ++i) {
      a[i] = *reinterpret_cast<const short8v*>(&As[buf][a_off[i]]);
      b[i] = *reinterpret_cast<const short8v*>(&Bs[buf][b_off[i]]);
    }
#pragma unroll
    for (int mi = 0; mi < 4; ++mi)
#pragma unroll
      for (int ni = 0; ni < 4; ++ni)
        acc[mi][ni] = __builtin_amdgcn_mfma_f32_16x16x32_bf16(
            a[mi], b[ni], acc[mi][ni], 0, 0, 0);
  }

  // Epilogue: C/D layout col=lane&15, row=(lane>>4)*4+j  [m89]
  // Split-K partial -> atomic accumulate (y pre-zeroed; distinct addresses,
  // max 27/KPG-way same-address contention).
#pragma unroll
  for (int mi = 0; mi < 4; ++mi) {
    const int rbase = row0 + wr * 64 + mi * 16 + ((lane >> 4) << 2);
#pragma unroll
    for (int ni = 0; ni < 4; ++ni) {
      const int col = col0 + wc * 64 + ni * 16 + (lane & 15);
#pragma unroll
      for (int j = 0; j < 4; ++j) {
        const int r = rbase + j;
        if (r < n_out) atomicAdd(&y[(size_t)r * Cout + col], acc[mi][ni][j]);
      }
    }
  }
}

// ---------------------------------------------------------------------------
__global__ void colstats_kernel(const float* __restrict__ y, int n, int C,
                                double* __restrict__ sums) {
  const int c = threadIdx.x;  // blockDim.x == C
  const int r0 = blockIdx.x * 64;
  const int r1 = min(r0 + 64, n);
  double s = 0.0, s2 = 0.0;
  for (int r = r0; r < r1; ++r) {
    float v = y[(size_t)r * C + c];
    s += v;
    s2 += (double)v * (double)v;
  }
  atomicAdd(&sums[c], s);
  atomicAdd(&sums[C + c], s2);
}

__global__ void finalize_kernel(const double* __restrict__ sums,
                                const float* __restrict__ g,
                                const float* __restrict__ b,
                                float* __restrict__ scale,
                                float* __restrict__ shift, int n, int C) {
  int c = blockIdx.x * blockDim.x + threadIdx.x;
  if (c >= C) return;
  double m = sums[c] / n;
  double v = sums[C + c] / n - m * m;
  float sc = (float)((double)g[c] / sqrt(v + 1e-5));
  scale[c] = sc;
  shift[c] = b[c] - (float)m * sc;
}

__global__ void bn_relu_pool_kernel(const float* __restrict__ y,
                                    const float* __restrict__ scale,
                                    const float* __restrict__ shift,
                                    const int* __restrict__ parent,
                                    unsigned int* __restrict__ pooled, int n,
                                    int C) {
  int i4 = (blockIdx.x * blockDim.x + threadIdx.x) * 4;
  if (i4 >= n * C) return;
  int r = i4 / C, c = i4 % C;
  float4 v = *reinterpret_cast<const float4*>(y + i4);
  float4 sc = *reinterpret_cast<const float4*>(scale + c);
  float4 sh = *reinterpret_cast<const float4*>(shift + c);
  unsigned int* dst = pooled + (size_t)parent[r] * C + c;
  atomicMax(dst + 0, __float_as_uint(fmaxf(fmaf(v.x, sc.x, sh.x), 0.f)));
  atomicMax(dst + 1, __float_as_uint(fmaxf(fmaf(v.y, sc.y, sh.y), 0.f)));
  atomicMax(dst + 2, __float_as_uint(fmaxf(fmaf(v.z, sc.z, sh.z), 0.f)));
  atomicMax(dst + 3, __float_as_uint(fmaxf(fmaf(v.w, sc.w, sh.w), 0.f)));
}

__global__ void bn_relu_bf16_kernel(const float* __restrict__ y,
                                    const float* __restrict__ scale,
                                    const float* __restrict__ shift,
                                    unsigned short* __restrict__ xb, int total,
                                    int C) {
  int i4 = (blockIdx.x * blockDim.x + threadIdx.x) * 4;
  if (i4 >= total) return;
  int c = i4 % C;
  float4 v = *reinterpret_cast<const float4*>(y + i4);
  float4 sc = *reinterpret_cast<const float4*>(scale + c);
  float4 sh = *reinterpret_cast<const float4*>(shift + c);
  ushort4 o = {f2bf(fmaxf(fmaf(v.x, sc.x, sh.x), 0.f)),
               f2bf(fmaxf(fmaf(v.y, sc.y, sh.y), 0.f)),
               f2bf(fmaxf(fmaf(v.z, sc.z, sh.z), 0.f)),
               f2bf(fmaxf(fmaf(v.w, sc.w, sh.w), 0.f))};
  *reinterpret_cast<ushort4*>(xb + i4) = o;
}

// ---------------------------------------------------------------------------
extern "C" void kernel_launch(void* const* d_in, const int* in_sizes, int n_in_,
                              void* d_out, int out_size, void* d_ws,
                              size_t ws_size, hipStream_t stream) {
  const float* feats = (const float*)d_in[0];
  const float* W1 = (const float*)d_in[1];
  const float* g1 = (const float*)d_in[2];
  const float* b1 = (const float*)d_in[3];
  const float* W2 = (const float*)d_in[4];
  const float* g2 = (const float*)d_in[5];
  const float* b2 = (const float*)d_in[6];
  const float* W3 = (const float*)d_in[7];
  const float* g3 = (const float*)d_in[8];
  const float* b3 = (const float*)d_in[9];
  const float* W4 = (const float*)d_in[10];
  const int* in1 = (const int*)d_in[11];
  const int* out1 = (const int*)d_in[12];
  const int* in2 = (const int*)d_in[13];
  const int* out2 = (const int*)d_in[14];
  const int* parent = (const int*)d_in[15];

  const int N1 = in_sizes[0] / 128;        // 60000
  const int M1 = in_sizes[11] / K_OFF;
  const int M2 = in_sizes[13] / K_OFF;
  const int NP = out_size / 256;           // n_pool

  const int n1_blocks = (N1 + 127) / 128, n1_pad = n1_blocks * 128;
  const int np_blocks = (NP + 127) / 128, np_pad = np_blocks * 128;

  auto rnd = [](size_t v) { return (v + 255) & ~size_t(255); };
  auto mx = [](size_t a, size_t b) { return a > b ? a : b; };
  char* ws = (char*)d_ws;
  size_t off = 0;
  auto take = [&](size_t b) { void* p = ws + off; off += rnd(b); return p; };

  const size_t sz_y1 = (size_t)N1 * 128 * 4;
  const size_t sz_y23 = (size_t)NP * 256 * 4;
  const size_t sz_x1 = ((size_t)N1 + 1) * 128 * 2;
  const size_t sz_x23 = ((size_t)NP + 1) * 256 * 2;
  const size_t sz_t1 = (size_t)K_OFF * n1_pad * 4;
  const size_t sz_t2 = (size_t)K_OFF * np_pad * 4;
  const size_t sz_pool = (size_t)NP * 128 * 4;
  const size_t sz_poolbf = ((size_t)NP + 1) * 128 * 2;
  const size_t sz_wt2 = (size_t)K_OFF * 128 * 256 * 2;
  const size_t sz_wt34 = (size_t)K_OFF * 256 * 256 * 2;

  // Slab A: y1  ->  {y2, y3}
  char* A = (char*)take(mx(rnd(sz_y1), 2 * rnd(sz_y23)));
  float* y1 = (float*)A;
  float* y2 = (float*)A;
  float* y3 = (float*)(A + rnd(sz_y23));
  // Slab B: x1b  ->  {Wt2, Wt3, Wt4, poolbf}   (Wt2-4 transposed AFTER conv1)
  char* B = (char*)take(
      mx(rnd(sz_x1), rnd(sz_wt2) + 2 * rnd(sz_wt34) + rnd(sz_poolbf)));
  unsigned short* x1b = (unsigned short*)B;
  unsigned short* Wt2 = (unsigned short*)B;
  unsigned short* Wt3 = (unsigned short*)(B + rnd(sz_wt2));
  unsigned short* Wt4 = (unsigned short*)(B + rnd(sz_wt2) + rnd(sz_wt34));
  unsigned short* poolbf =
      (unsigned short*)(B + rnd(sz_wt2) + 2 * rnd(sz_wt34));
  // Slab C: table1 -> pooled -> x2b -> x3b
  char* C = (char*)take(mx(rnd(sz_t1), mx(rnd(sz_pool), rnd(sz_x23))));
  int* table1 = (int*)C;
  float* pooled = (float*)C;
  unsigned short* x2b = (unsigned short*)C;
  unsigned short* x3b = (unsigned short*)C;
  // Persistent
  int* table2 = (int*)take(sz_t2);
  unsigned short* Wt1 = (unsigned short*)take((size_t)K_OFF * 128 * 128 * 2);
  double* sums = (double*)take(3 * 512 * 8);
  double* sums1 = sums; double* sums2 = sums + 512; double* sums3 = sums + 1024;
  float* scsh = (float*)take(6 * 256 * 4);
  float* sc1 = scsh;        float* sh1 = scsh + 256;
  float* sc2 = scsh + 512;  float* sh2 = scsh + 768;
  float* sc3 = scsh + 1024; float* sh3 = scsh + 1280;

  dim3 wtb(32, 8);
  wtrans_kernel<<<dim3(4, 4, K_OFF), wtb, 0, stream>>>(W1, Wt1, 128, 128);

  f32_to_bf16_kernel<<<(N1 * 128 / 4 + 255) / 256, 256, 0, stream>>>(
      feats, x1b, N1 * 128);
  hipMemsetAsync(x1b + (size_t)N1 * 128, 0, 128 * 2, stream);

  fill_i32_kernel<<<(K_OFF * n1_pad + 255) / 256, 256, 0, stream>>>(
      table1, K_OFF * n1_pad, N1);
  fill_i32_kernel<<<(K_OFF * np_pad + 255) / 256, 256, 0, stream>>>(
      table2, K_OFF * np_pad, NP);
  build_table_kernel<<<(K_OFF * M1 + 255) / 256, 256, 0, stream>>>(
      in1, out1, table1, M1, N1, n1_pad);
  build_table_kernel<<<(K_OFF * M2 + 255) / 256, 256, 0, stream>>>(
      in2, out2, table2, M2, NP, np_pad);
  hipMemsetAsync(sums, 0, 3 * 512 * 8, stream);

  // conv1: 128 -> 128, split-K G=3 (KPG=9) -> 1407 WGs
  hipMemsetAsync(y1, 0, sz_y1, stream);
  spconv_mfma<128, 9><<<dim3(n1_blocks, 1, 3), 256, 0, stream>>>(
      x1b, Wt1, table1, y1, N1, n1_pad, 128);
  colstats_kernel<<<(N1 + 63) / 64, 128, 0, stream>>>(y1, N1, 128, sums1);
  finalize_kernel<<<1, 128, 0, stream>>>(sums1, g1, b1, sc1, sh1, N1, 128);
  // Wt2-4 into old x1b space (x1b dead after conv1; stream-ordered)
  wtrans_kernel<<<dim3(4, 8, K_OFF), wtb, 0, stream>>>(W2, Wt2, 128, 256);
  wtrans_kernel<<<dim3(8, 8, K_OFF), wtb, 0, stream>>>(W3, Wt3, 256, 256);
  wtrans_kernel<<<dim3(8, 8, K_OFF), wtb, 0, stream>>>(W4, Wt4, 256, 256);
  // pooled into old table1 space (table1 dead after conv1)
  hipMemsetAsync(pooled, 0, sz_pool, stream);
  bn_relu_pool_kernel<<<((N1 * 128 / 4) + 255) / 256, 256, 0, stream>>>(
      y1, sc1, sh1, parent, (unsigned int*)pooled, N1, 128);
  f32_to_bf16_kernel<<<((NP * 128 / 4) + 255) / 256, 256, 0, stream>>>(
      pooled, poolbf, NP * 128);
  hipMemsetAsync(poolbf + (size_t)NP * 128, 0, 128 * 2, stream);

  // conv2: 128 -> 256, split-K G=9 (KPG=3) -> 1476 WGs
  hipMemsetAsync(y2, 0, sz_y23, stream);   // after bn_relu_pool (y1 dead)
  spconv_mfma<128, 3><<<dim3(np_blocks, 2, 9), 256, 0, stream>>>(
      poolbf, Wt2, table2, y2, NP, np_pad, 256);
  colstats_kernel<<<(NP + 63) / 64, 256, 0, stream>>>(y2, NP, 256, sums2);
  finalize_kernel<<<1, 256, 0, stream>>>(sums2, g2, b2, sc2, sh2, NP, 256);
  bn_relu_bf16_kernel<<<((NP * 256 / 4) + 255) / 256, 256, 0, stream>>>(
      y2, sc2, sh2, x2b, NP * 256, 256);   // x2b overwrites pooled (dead)
  hipMemsetAsync(x2b + (size_t)NP * 256, 0, 256 * 2, stream);

  // conv3: 256 -> 256, split-K G=9
  hipMemsetAsync(y3, 0, sz_y23, stream);
  spconv_mfma<256, 3><<<dim3(np_blocks, 2, 9), 256, 0, stream>>>(
      x2b, Wt3, table2, y3, NP, np_pad, 256);
  colstats_kernel<<<(NP + 63) / 64, 256, 0, stream>>>(y3, NP, 256, sums3);
  finalize_kernel<<<1, 256, 0, stream>>>(sums3, g3, b3, sc3, sh3, NP, 256);
  bn_relu_bf16_kernel<<<((NP * 256 / 4) + 255) / 256, 256, 0, stream>>>(
      y3, sc3, sh3, x3b, NP * 256, 256);   // x3b overwrites x2b (dead)
  hipMemsetAsync(x3b + (size_t)NP * 256, 0, 256 * 2, stream);

  // conv4: 256 -> 256, split-K G=9 -> d_out (pre-zeroed: harness poisons it)
  hipMemsetAsync(d_out, 0, (size_t)out_size * 4, stream);
  spconv_mfma<256, 3><<<dim3(np_blocks, 2, 9), 256, 0, stream>>>(
      x3b, Wt4, table2, (float*)d_out, NP, np_pad, 256);
}